// Round 15
// baseline (102.180 us; speedup 1.0000x reference)
//
#include <hip/hip_runtime.h>
#include <cstddef>

// Problem constants (match reference)
#define T_STEPS 32
#define B_SZ    512
#define S_SZ    64
#define F_INPUT 128
#define H1      256
#define H2      256
#define H3      128

typedef _Float16 half_t;
typedef __attribute__((ext_vector_type(8))) _Float16 half8;
typedef __attribute__((ext_vector_type(4))) float   float4v;

// ---------------------------------------------------------------------------
// Swizzled-W replication. R15 CHANGE: 8 address-disjoint copies of the
// swizzled hi/lo weight tables. Theory: every variant R4..R14 ran the GEMM
// phase at a ~5-10x latency multiplier invariant to occupancy/volume/barriers
// — all blocks are device-phase-locked and demand the SAME W lines from each
// XCD L2 within ~100 cyc (32 CUs/L2 burst => ~1000 cyc queueing). Copies
// spread the burst 8x. Values identical -> bit-exact vs R14.
// Rep r at ws + r*512 KB; within a rep: ws1 at +0, ws2 at +128 KB, ws3 at
// +384 KB. Block b uses rep (b>>3)&7 ((b&7) would map 1:1 to XCDs and keep
// all CUs of an XCD on one copy — (b>>3) cycles copies WITHIN an XCD).
// ---------------------------------------------------------------------------
#define REP_HALFS (262144)   // 512 KB / sizeof(half)
#define N_REPS    8

__device__ inline void split_store_sw(float w, half_t* out, int n, int k, int kchunks) {
    half_t hi = (half_t)w;
    float hif = (float)hi;
    if (fabsf(hif) < 6.103515625e-05f) { hi = (half_t)0.0f; hif = 0.0f; }
    half_t lo = (half_t)((w - hif) * 4096.0f);
    int n_tile = n >> 4, lr = n & 15;
    int k_chunk = k >> 5, kin = k & 31, quad = kin >> 3, j = kin & 7;
    size_t base = (size_t)(n_tile * kchunks + k_chunk) * 1024;
    size_t off  = base + (size_t)((quad << 4) + lr) * 8 + j;
#pragma unroll
    for (int r = 0; r < N_REPS; ++r) {
        out[(size_t)r * REP_HALFS + off]       = hi;
        out[(size_t)r * REP_HALFS + off + 512] = lo;
    }
}

__global__ __launch_bounds__(256)
void prep_w_kernel(const float* __restrict__ W1, const float* __restrict__ W2,
                   const float* __restrict__ W3, half_t* __restrict__ wsw) {
    half_t* ws1 = wsw;                       // +0
    half_t* ws2 = wsw + 65536;               // +128 KB
    half_t* ws3 = wsw + 196608;              // +384 KB
    int e = blockIdx.x * blockDim.x + threadIdx.x;   // 0..131071
    if (e < H1 * F_INPUT) {                          // 256 x 128, kchunks=4
        split_store_sw(W1[e], ws1, e / F_INPUT, e % F_INPUT, F_INPUT / 32);
    } else if (e < H1 * F_INPUT + H2 * H1) {         // 256 x 256, kchunks=8
        int i = e - H1 * F_INPUT;
        split_store_sw(W2[i], ws2, i / H1, i % H1, H1 / 32);
    } else {                                         // 128 x 256, kchunks=8
        int i = e - H1 * F_INPUT - H2 * H1;
        split_store_sw(W3[i], ws3, i / H2, i % H2, H2 / 32);
    }
}

// ---------------------------------------------------------------------------
// LDS geometry (unchanged from R14 — correct, race-free, absmax 0).
// ---------------------------------------------------------------------------
#define AS_STRIDE  136   // halfs, rates rows (K=128 +8 pad)
#define SPK_STRIDE 264   // halfs, spike rows (K=256 +8 pad)
#define CUR_STRIDE 260   // floats, cur rows (256 cols + 4 pad) — injective
#define SMEM_AS    0         // 32*136*2 = 8704 B
#define SMEM_CUR   8704      // 32*260*4 = 33280 B
#define SMEM_SPKA  41984     // 32*264*2 = 16896 B
#define SMEM_SPKB  58880     // 32*264*2 = 16896 B
#define SMEM_TOTAL 75776     // 74 KB -> 2 blocks/CU (148 KB < 160)
// hist/minmax scratch (32 KB) aliases curT only, dead before L1.

// Per-wave fused GEMM + LIF (unchanged from R14 — bit-exact chain).
template<int KCHUNKS, int NT, int ASTRIDE, int FINAL>
__device__ __forceinline__ void gemm_lif_wave(const half_t* __restrict__ Wsw,
                                              const float*  __restrict__ bias,
                                              const half_t* __restrict__ Als,
                                              float*  __restrict__ curT,
                                              half_t* __restrict__ spk_out,
                                              float*  __restrict__ out_final,
                                              int b, int wave, int lane) {
    const int quad = lane >> 4, lr = lane & 15;
    float4v acc_h[2][NT], acc_l[2][NT];
#pragma unroll
    for (int mt = 0; mt < 2; ++mt)
#pragma unroll
        for (int nt = 0; nt < NT; ++nt) {
            acc_h[mt][nt] = (float4v){0.0f, 0.0f, 0.0f, 0.0f};
            acc_l[mt][nt] = (float4v){0.0f, 0.0f, 0.0f, 0.0f};
        }

    half8 wh[NT], wl[NT];
#pragma unroll
    for (int nt = 0; nt < NT; ++nt) {
        const half_t* p = Wsw + ((size_t)(wave * NT + nt) * KCHUNKS) * 1024 + lane * 8;
        wh[nt] = *(const half8*)(p);
        wl[nt] = *(const half8*)(p + 512);
    }
#pragma unroll
    for (int c = 0; c < KCHUNKS; ++c) {
        half8 a[2];
#pragma unroll
        for (int mt = 0; mt < 2; ++mt)
            a[mt] = *(const half8*)(Als + (mt * 16 + lr) * ASTRIDE + c * 32 + quad * 8);
        half8 nwh[NT], nwl[NT];
        if (c + 1 < KCHUNKS) {
#pragma unroll
            for (int nt = 0; nt < NT; ++nt) {
                const half_t* p =
                    Wsw + ((size_t)(wave * NT + nt) * KCHUNKS + c + 1) * 1024 + lane * 8;
                nwh[nt] = *(const half8*)(p);
                nwl[nt] = *(const half8*)(p + 512);
            }
        }
#pragma unroll
        for (int nt = 0; nt < NT; ++nt)
#pragma unroll
            for (int mt = 0; mt < 2; ++mt) {
                acc_h[mt][nt] = __builtin_amdgcn_mfma_f32_16x16x32_f16(a[mt], wh[nt], acc_h[mt][nt], 0, 0, 0);
                acc_l[mt][nt] = __builtin_amdgcn_mfma_f32_16x16x32_f16(a[mt], wl[nt], acc_l[mt][nt], 0, 0, 0);
            }
#pragma unroll
        for (int nt = 0; nt < NT; ++nt) { wh[nt] = nwh[nt]; wl[nt] = nwl[nt]; }
    }

    // epilogue -> curT, own cols only (C/D layout: col=lane&15, row=quad*4+r)
#pragma unroll
    for (int nt = 0; nt < NT; ++nt) {
        int col = (wave * NT + nt) * 16 + lr;
        float bj = bias[col];
#pragma unroll
        for (int mt = 0; mt < 2; ++mt) {
            int rbase = mt * 16 + quad * 4;
#pragma unroll
            for (int r = 0; r < 4; ++r) {
                float v = acc_h[mt][nt][r] + 2.44140625e-04f * acc_l[mt][nt][r];
                curT[(rbase + r) * CUR_STRIDE + col] = v + bj;
            }
        }
    }

    // LIF scan of this wave's own cols — same-wave LDS dependency, no barrier.
    // fp contract OFF (reference mul/add/sub rounding at the threshold).
    if (lane < NT * 16) {
#pragma clang fp contract(off)
        const int col = wave * NT * 16 + lane;
        float mem = 0.0f;
#pragma unroll
        for (int t = 0; t < T_STEPS; ++t) {
            float c = curT[t * CUR_STRIDE + col];
            float reset = (mem - 1.0f > 0.0f) ? 1.0f : 0.0f;
            float p = 0.9f * mem;
            p = p + c;
            mem = p - reset;
            float s = (mem - 1.0f > 0.0f) ? 1.0f : 0.0f;
            if (FINAL) {
                // reference output layout: [t*B + b][h], f32
                out_final[((size_t)t * B_SZ + b) * H3 + col] = s;
            } else {
                spk_out[t * SPK_STRIDE + col] = (half_t)s;
            }
        }
    }
}

// ---------------------------------------------------------------------------
// Mega kernel: one block = one batch b, 512 threads (8 waves), per-wave
// staggered GEMM+scan pipelines; W read from per-block replica.
// ---------------------------------------------------------------------------
__global__ __launch_bounds__(512, 4)
void snn_mega_kernel(const float* __restrict__ x,
                     const half_t* __restrict__ wsw,
                     const float* __restrict__ b1,
                     const float* __restrict__ b2,
                     const float* __restrict__ b3,
                     float* __restrict__ out) {
    __shared__ __align__(16) char smem[SMEM_TOTAL];
    half_t* As   = (half_t*)(smem + SMEM_AS);
    float*  curT = (float*) (smem + SMEM_CUR);
    half_t* spkA = (half_t*)(smem + SMEM_SPKA);
    half_t* spkB = (half_t*)(smem + SMEM_SPKB);
    float*  scratch = (float*)(smem + SMEM_CUR);   // pre-L1: minmax + hist

    const int tid  = threadIdx.x;
    const int b    = blockIdx.x;
    const int wave = tid >> 6;
    const int lane = tid & 63;

    // per-block W replica: (b>>3)&7 cycles copies across CUs within an XCD
    const half_t* wrep = wsw + (size_t)((b >> 3) & (N_REPS - 1)) * REP_HALFS;
    const half_t* ws1 = wrep;                 // +0
    const half_t* ws2 = wrep + 65536;         // +128 KB
    const half_t* ws3 = wrep + 196608;        // +384 KB

    // ================= phase 0: latency encode (threads 0..255) ===========
    const int f  = tid & 127;
    const int sh = (tid >> 7) & 1;               // s-half: 0 -> s 0..31, 1 -> 32..63
    const float* xp = x + (size_t)b * (S_SZ * F_INPUT) + (size_t)sh * 32 * F_INPUT + f;

    float v[32];                                 // burst loads, all in flight
    float fmn = 0.0f, fmx = 0.0f;
    if (tid < 256) {
#pragma unroll
        for (int s = 0; s < 32; ++s) {
            float val = xp[(size_t)s * F_INPUT];
            v[s] = (val < 0.75f) ? 0.0f : val;   // gate at ENC_THR
        }
        float mn = 1e30f, mx = -1e30f;
#pragma unroll
        for (int s = 0; s < 32; ++s) {
            mn = fminf(mn, v[s]);
            mx = fmaxf(mx, v[s]);
        }
        scratch[sh * 128 + f]       = mn;
        scratch[256 + sh * 128 + f] = mx;
    }
    __syncthreads();
    if (tid < 256) {
        // exact: min(min half0, min half1) == min(all); same for max
        fmn = fminf(scratch[f], scratch[128 + f]);
        fmx = fmaxf(scratch[256 + f], scratch[384 + f]);
    }
    __syncthreads();

    if (tid < 256) {
        float* hist = scratch;                   // hist[2][32][128] f32 (32 KB)
#pragma unroll
        for (int t = 0; t < T_STEPS; ++t) hist[sh * 4096 + t * 128 + f] = 0.0f;
        // no barrier: each thread touches only its own (sh,*,f) cells
        const float denom = fmx - fmn + 1e-8f;
#pragma unroll
        for (int s = 0; s < 32; ++s) {
            float g  = v[s];
            float xn = (g - fmn) / denom;
            float d  = fmaxf(xn, 0.0100001f);        // clip(xn, LAT_THR+EPS)
            float tt = logf(d / (d - 0.01f));        // log latency code
            tt = tt * 31.0f;
            tt = tt / 11.512935464920229f;           // float32(log((thr+eps)/eps))
            float tr = rintf(tt);                    // half-to-even == jnp.round
            tr = fminf(fmaxf(tr, 0.0f), 31.0f);
            hist[sh * 4096 + (int)tr * 128 + f] += 1.0f;
        }
    }
    __syncthreads();

    // merge halves -> rates (exact k/64) into As (separate region: no barrier
    // needed between hist reads and As writes)
    if (tid < 256) {
#pragma unroll
        for (int i = 0; i < 16; ++i) {
            int idx = tid + i * 256;             // 0..4095
            int t = idx >> 7, ff = idx & 127;
            float cnt = scratch[t * 128 + ff] + scratch[4096 + t * 128 + ff];
            As[t * AS_STRIDE + ff] = (half_t)(cnt * 0.015625f);
        }
    }
    __syncthreads();   // As complete; hist region (curT) now dead

    // ================= layer 1: per-wave GEMM+LIF, K=128, N=256 ===========
    gemm_lif_wave<F_INPUT / 32, 2, AS_STRIDE, 0>(ws1, b1, As, curT, spkA, nullptr,
                                                 b, wave, lane);
    __syncthreads();   // all spkA cols written

    // ================= layer 2: per-wave GEMM+LIF, K=256, N=256 ===========
    gemm_lif_wave<H1 / 32, 2, SPK_STRIDE, 0>(ws2, b2, spkA, curT, spkB, nullptr,
                                             b, wave, lane);
    __syncthreads();   // all spkB cols written

    // ================= layer 3: per-wave GEMM+LIF -> out, K=256, N=128 ====
    gemm_lif_wave<H2 / 32, 1, SPK_STRIDE, 1>(ws3, b3, spkB, curT, nullptr, out,
                                             b, wave, lane);
}

// ---------------------------------------------------------------------------
extern "C" void kernel_launch(void* const* d_in, const int* in_sizes, int n_in,
                              void* d_out, int out_size, void* d_ws, size_t ws_size,
                              hipStream_t stream) {
    const float* x  = (const float*)d_in[0];
    const float* W1 = (const float*)d_in[1];
    const float* b1 = (const float*)d_in[2];
    const float* W2 = (const float*)d_in[3];
    const float* b2 = (const float*)d_in[4];
    const float* W3 = (const float*)d_in[5];
    const float* b3 = (const float*)d_in[6];
    float* out = (float*)d_out;

    half_t* wsw = (half_t*)d_ws;   // 8 replicas x 512 KB = 4 MB

    // 0. split + swizzle + replicate weights (one dispatch, all layers)
    prep_w_kernel<<<(H1 * F_INPUT + H2 * H1 + H3 * H2) / 256, 256, 0, stream>>>(
        W1, W2, W3, wsw);

    // 1. whole network: one block per batch, per-wave staggered pipelines,
    //    per-block W replica breaks device-wide same-line L2 bursts
    snn_mega_kernel<<<B_SZ, 512, 0, stream>>>(x, wsw, b1, b2, b3, out);
}